// Round 10
// baseline (100.762 us; speedup 1.0000x reference)
//
#include <hip/hip_runtime.h>
#include <hip/hip_bf16.h>
#include <math.h>

typedef float v4f   __attribute__((ext_vector_type(4)));
typedef float f32x4 __attribute__((ext_vector_type(4)));
typedef short s16x8 __attribute__((ext_vector_type(8)));
typedef __hip_bfloat16 bf16;

#define PI_F 3.14159265358979323846f

// B=2, L=2048, D=256, K=32. Half-chunks: 16 rows, 128/batch (encode grain).
// Output chunks: 32 rows, 64/batch. PF = chunk-level exclusive prefix (bf16).

__device__ inline unsigned short f2bf(float f) {
    unsigned int b = __float_as_uint(f);
    unsigned int r = (b + 0x7FFFu + ((b >> 16) & 1u)) >> 16;   // RNE
    return (unsigned short)r;
}
__device__ inline float bf2f(unsigned short u) {
    return __uint_as_float(((unsigned int)u) << 16);
}
__device__ inline void cvt8(const float* __restrict__ src, unsigned short* dst) {
    v4f a = *(const v4f*)src, b = *(const v4f*)(src + 4);
    ushort4 u0, u1;
    u0.x = f2bf(a[0]); u0.y = f2bf(a[1]); u0.z = f2bf(a[2]); u0.w = f2bf(a[3]);
    u1.x = f2bf(b[0]); u1.y = f2bf(b[1]); u1.z = f2bf(b[2]); u1.w = f2bf(b[3]);
    *(ushort4*)dst = u0; *(ushort4*)(dst + 4) = u1;
}

// RMW-free grid barrier (R7/R8 post-mortem: 256 serialized fetch_adds on one
// line = ~60us/barrier; atomic STORES to distinct words don't serialize).
// Arrival: relaxed store flags[bid]=epoch. Detection: block 0 wave 0 scans
// 256 flags lane-parallel. Release: single 'go' store; consumers poll 'go'
// read-only. Fences: once per block (thread 0) — __syncthreads has already
// drained vmcnt, so one wbl2/inv covers all the block's traffic.
__device__ inline void gridbar(int* flags, int* go, int epoch) {
    __syncthreads();
    const int tid = threadIdx.x, bid = blockIdx.x;
    if (tid == 0) {
        __threadfence();                       // release: L2 -> LLC
        __hip_atomic_store(&flags[bid], epoch, __ATOMIC_RELAXED,
                           __HIP_MEMORY_SCOPE_AGENT);
    }
    if (bid == 0 && tid < 64) {
        for (;;) {
            int ok = 1;
            #pragma unroll
            for (int j = 0; j < 4; ++j)
                ok &= (__hip_atomic_load(&flags[tid + 64 * j], __ATOMIC_RELAXED,
                                         __HIP_MEMORY_SCOPE_AGENT) >= epoch);
            if (__all(ok)) break;
            __builtin_amdgcn_s_sleep(1);
        }
        if (tid == 0)
            __hip_atomic_store(go, epoch, __ATOMIC_RELAXED,
                               __HIP_MEMORY_SCOPE_AGENT);
    }
    if (tid == 0) {
        while (__hip_atomic_load(go, __ATOMIC_RELAXED,
                                 __HIP_MEMORY_SCOPE_AGENT) < epoch)
            __builtin_amdgcn_s_sleep(2);
        __threadfence();                       // acquire: inv L1/L2
    }
    __syncthreads();
}

__global__ __launch_bounds__(512) void k_mega(
    const float* __restrict__ X,
    const float* __restrict__ kw1, const float* __restrict__ kb1,
    const float* __restrict__ kw2, const float* __restrict__ kb2,
    const float* __restrict__ qw1, const float* __restrict__ qb1,
    const float* __restrict__ qw2, const float* __restrict__ qb2,
    const float* __restrict__ vw,  const float* __restrict__ vb,
    float* __restrict__ KP, float* __restrict__ QP,
    bf16* __restrict__ Wb, bf16* __restrict__ W2b, bf16* __restrict__ Vb,
    bf16* __restrict__ SRg, bf16* __restrict__ SIg,
    bf16* __restrict__ PFR, bf16* __restrict__ PFI,
    float* __restrict__ out, int* __restrict__ bar)
{
    __shared__ __align__(16) unsigned char smem[74240];
    const int tid = threadIdx.x, bid = blockIdx.x;
    int* flags = bar;
    int* go    = bar + 320;

    // ================= Phase 0: weight conversion (fp32 -> bf16) ==========
    {
        int gid = bid * 512 + tid;          // 832 rows * 32 groups-of-8
        if (gid < 26624) {
            int r = gid >> 5, c8 = (gid & 31) * 8;
            const float* src; unsigned short* dst;
            if (r < 768) {
                src = (r < 256) ? kw1 + (size_t)r * 256
                    : (r < 512) ? qw1 + (size_t)(r - 256) * 256
                                : vw  + (size_t)(r - 512) * 256;
                dst = (unsigned short*)Wb + (size_t)r * 256;
            } else {
                int r2 = r - 768;
                src = (r2 < 32) ? kw2 + (size_t)r2 * 256
                                : qw2 + (size_t)(r2 - 32) * 256;
                dst = (unsigned short*)W2b + (size_t)r2 * 256;
            }
            cvt8(src + c8, dst + c8);
        }
    }
    gridbar(flags, go, 1);

    // ================= Phase 1: encode one 16-row half-chunk ==============
    {
        unsigned short* Abf = (unsigned short*)smem;            // [16][264]
        unsigned short* Hkq = (unsigned short*)(smem + 8448);   // [16][520]
        unsigned short* Vt  = (unsigned short*)(smem + 25088);  // [256][40]
        unsigned short* CKc = (unsigned short*)(smem + 45568);  // [32][40]
        unsigned short* CKs = (unsigned short*)(smem + 48128);  // [32][40]
        const int lane = tid & 63, wid = tid >> 6;              // 8 waves
        const int lrow = lane & 15, lk8 = (lane >> 4) * 8, t0 = (lane >> 4) * 4;
        const int bb = bid >> 7, hc = bid & 127;
        const int row0 = bb * 2048 + hc * 16;

        {   // stage X tile (16x256 fp32 -> bf16 LDS)
            int r = tid >> 5, c8 = (tid & 31) * 8;
            cvt8(X + (size_t)(row0 + r) * 256 + c8, &Abf[r * 264 + c8]);
        }
        {   // zero t=16..31 pads (GEMM3 runs K=32 over 16 real t rows)
            s16x8 z = {};
            { int r = tid >> 1, h = tid & 1; *(s16x8*)&Vt[r * 40 + 16 + h * 8] = z; }
            if (tid < 64)       { int r = tid >> 1, h = tid & 1;
                                  *(s16x8*)&CKc[r * 40 + 16 + h * 8] = z; }
            else if (tid < 128) { int r = (tid - 64) >> 1, h = tid & 1;
                                  *(s16x8*)&CKs[r * 40 + 16 + h * 8] = z; }
        }
        __syncthreads();

        // ---- GEMM1: wave owns 96 cols of [kw1|qw1|vw]^T ----
        const int nb = wid * 96;
        const unsigned short* Wu = (const unsigned short*)Wb;
        f32x4 acc[6] = {};
        for (int k0 = 0; k0 < 256; k0 += 32) {
            s16x8 a = *(const s16x8*)&Abf[lrow * 264 + k0 + lk8];
            #pragma unroll
            for (int nf = 0; nf < 6; ++nf) {
                s16x8 b = *(const s16x8*)(Wu + (size_t)(nb + nf * 16 + lrow) * 256 + k0 + lk8);
                acc[nf] = __builtin_amdgcn_mfma_f32_16x16x32_bf16(a, b, acc[nf], 0, 0, 0);
            }
        }
        // ---- epilogue: Hkq (tanh, bf16 LDS) / Vt (LDS) + Vb (global) ----
        #pragma unroll
        for (int nf = 0; nf < 6; ++nf) {
            int n = nb + nf * 16 + lrow;
            float bias = (n < 256) ? kb1[n] : (n < 512) ? qb1[n - 256] : vb[n - 512];
            if (n < 512) {
                #pragma unroll
                for (int r = 0; r < 4; ++r)
                    Hkq[(t0 + r) * 520 + n] = f2bf(tanhf(acc[nf][r] + bias));
            } else {
                int d = n - 512;
                ushort4 u;
                u.x = f2bf(acc[nf][0] + bias); u.y = f2bf(acc[nf][1] + bias);
                u.z = f2bf(acc[nf][2] + bias); u.w = f2bf(acc[nf][3] + bias);
                *(ushort4*)&Vt[d * 40 + t0] = u;
                unsigned short* Vg = (unsigned short*)Vb + (size_t)(row0 + t0) * 256 + d;
                Vg[0] = u.x; Vg[256] = u.y; Vg[512] = u.z; Vg[768] = u.w;
            }
        }
        __syncthreads();

        // ---- GEMM2 (waves 0-3): layer-2 + trig -> KP/QP global, CK LDS ----
        if (wid < 4) {
            const int which = wid >> 1, nf = wid & 1;
            const unsigned short* W2u = (const unsigned short*)W2b
                + (size_t)(which * 32 + nf * 16 + lrow) * 256;
            f32x4 u = {};
            for (int k0 = 0; k0 < 256; k0 += 32) {
                s16x8 a = *(const s16x8*)&Hkq[lrow * 520 + which * 256 + k0 + lk8];
                s16x8 b = *(const s16x8*)(W2u + k0 + lk8);
                u = __builtin_amdgcn_mfma_f32_16x16x32_bf16(a, b, u, 0, 0, 0);
            }
            const int outk = nf * 16 + lrow;
            const float bias = (which ? qb2 : kb2)[outk];
            float* dst = which ? QP : KP;
            float cs[4], sn[4];
            #pragma unroll
            for (int r = 0; r < 4; ++r) {
                float ph = tanhf(u[r] + bias) * PI_F;
                __sincosf(ph, &sn[r], &cs[r]);
                int row = row0 + t0 + r;
                dst[(size_t)row * 64 + outk]      = cs[r];
                dst[(size_t)row * 64 + 32 + outk] = sn[r];
            }
            if (which == 0) {
                ushort4 uc, us;
                uc.x = f2bf(cs[0]); uc.y = f2bf(cs[1]); uc.z = f2bf(cs[2]); uc.w = f2bf(cs[3]);
                us.x = f2bf(sn[0]); us.y = f2bf(sn[1]); us.z = f2bf(sn[2]); us.w = f2bf(sn[3]);
                *(ushort4*)&CKc[outk * 40 + t0] = uc;
                *(ushort4*)&CKs[outk * 40 + t0] = us;
            }
        }
        __syncthreads();

        // ---- GEMM3 (all 8 waves): half-chunk sums; wave owns 32 d-cols ----
        {
            f32x4 zz = {};
            s16x8 ac0 = *(const s16x8*)&CKc[lrow * 40 + lk8];
            s16x8 ac1 = *(const s16x8*)&CKc[(16 + lrow) * 40 + lk8];
            s16x8 as0 = *(const s16x8*)&CKs[lrow * 40 + lk8];
            s16x8 as1 = *(const s16x8*)&CKs[(16 + lrow) * 40 + lk8];
            unsigned short* SRu = (unsigned short*)SRg;
            unsigned short* SIu = (unsigned short*)SIg;
            #pragma unroll
            for (int nf = 0; nf < 2; ++nf) {
                int dcol = wid * 32 + nf * 16 + lrow;
                s16x8 bv = *(const s16x8*)&Vt[dcol * 40 + lk8];
                f32x4 r0 = __builtin_amdgcn_mfma_f32_16x16x32_bf16(ac0, bv, zz, 0, 0, 0);
                f32x4 r1 = __builtin_amdgcn_mfma_f32_16x16x32_bf16(ac1, bv, zz, 0, 0, 0);
                f32x4 i0 = __builtin_amdgcn_mfma_f32_16x16x32_bf16(as0, bv, zz, 0, 0, 0);
                f32x4 i1 = __builtin_amdgcn_mfma_f32_16x16x32_bf16(as1, bv, zz, 0, 0, 0);
                size_t base = (((size_t)(bb * 128 + hc)) * 32) * 256 + dcol;
                #pragma unroll
                for (int r = 0; r < 4; ++r) {
                    int ka = t0 + r, kb_ = 16 + t0 + r;
                    SRu[base + (size_t)ka  * 256] = f2bf(r0[r]);
                    SRu[base + (size_t)kb_ * 256] = f2bf(r1[r]);
                    SIu[base + (size_t)ka  * 256] = f2bf(i0[r]);
                    SIu[base + (size_t)kb_ * 256] = f2bf(i1[r]);
                }
            }
        }
    }
    gridbar(flags, go, 2);

    // ================= Phase 2: scan -> chunk-level exclusive prefix PF ===
    {
        int gid = bid * 512 + tid;    // 131072 = 2b * 2ri * 8seg * 4096 e2
        int e2 = gid & 4095, seg = (gid >> 12) & 7, ri = (gid >> 15) & 1, b = gid >> 16;
        const unsigned short* S = (const unsigned short*)(ri ? SIg : SRg);
        unsigned short* PF = (unsigned short*)(ri ? PFI : PFR);
        const size_t col = (size_t)e2 * 2;
        const size_t hbase = (size_t)(b * 128) * 8192 + col;
        float r0 = 0.f, r1 = 0.f;
        for (int hp = 0; hp < seg * 16; ++hp) {
            ushort2 u = *(const ushort2*)(S + hbase + (size_t)hp * 8192);
            r0 += bf2f(u.x); r1 += bf2f(u.y);
        }
        #pragma unroll
        for (int j = 0; j < 8; ++j) {
            int c = seg * 8 + j;
            ushort2 w; w.x = f2bf(r0); w.y = f2bf(r1);
            *(ushort2*)(PF + (size_t)(b * 64 + c) * 8192 + col) = w;
            ushort2 u0 = *(const ushort2*)(S + hbase + (size_t)(2 * c)     * 8192);
            ushort2 u1 = *(const ushort2*)(S + hbase + (size_t)(2 * c + 1) * 8192);
            r0 += bf2f(u0.x) + bf2f(u1.x);
            r1 += bf2f(u0.y) + bf2f(u1.y);
        }
    }
    gridbar(flags, go, 3);

    // ================= Phase 3: output (one 32-row chunk, 2 dh slices) ====
    {
        float* sm  = (float*)smem;
        float* QPc = sm;                         // [32][68] (dup-written)
        float* KPc = sm + 2176;
        float* Sl  = sm + 4352;                  // [32][36]
        const int group = tid >> 8, t256 = tid & 255;
        float* grp  = sm + 5504 + group * 6528;
        float* vall = grp;                       // [32][68]
        float* PRl  = grp + 2176;
        float* PIl  = grp + 4352;
        const int b = bid >> 7, c = (bid >> 1) & 63, dhh = bid & 1;
        const int dh = dhh * 2 + group;
        const int row0 = b * 2048 + c * 32;

        #pragma unroll
        for (int it = 0; it < 2; ++it) {
            int idx = t256 + it * 256, t = idx >> 4, j4 = idx & 15;
            *(v4f*)&QPc[t * 68 + j4 * 4] = *(const v4f*)(QP + (size_t)(row0 + t) * 64 + j4 * 4);
            *(v4f*)&KPc[t * 68 + j4 * 4] = *(const v4f*)(KP + (size_t)(row0 + t) * 64 + j4 * 4);
        }
        {   // V slice bf16 -> fp32 LDS
            int t = t256 >> 3, e8 = (t256 & 7) * 8;
            s16x8 u = *(const s16x8*)((const unsigned short*)Vb
                                      + (size_t)(row0 + t) * 256 + dh * 64 + e8);
            #pragma unroll
            for (int j = 0; j < 8; ++j) vall[t * 68 + e8 + j] = bf2f((unsigned short)u[j]);
        }
        {   // prefix state: direct PF read
            int k = t256 >> 3, dg = t256 & 7;
            size_t pb = ((size_t)(b * 64 + c)) * 8192 + k * 256 + dh * 64 + dg * 8;
            s16x8 ur = *(const s16x8*)((const unsigned short*)PFR + pb);
            s16x8 ui = *(const s16x8*)((const unsigned short*)PFI + pb);
            #pragma unroll
            for (int j = 0; j < 8; ++j) {
                PRl[k * 68 + dg * 8 + j] = bf2f((unsigned short)ur[j]);
                PIl[k * 68 + dg * 8 + j] = bf2f((unsigned short)ui[j]);
            }
        }
        __syncthreads();
        {   // S tile (32x32 causal) — both groups compute identical values
            const int sl = t256 >> 3, tq = t256 & 7;
            float s4[4] = {0.f, 0.f, 0.f, 0.f};
            for (int j4 = 0; j4 < 16; ++j4) {
                v4f q4 = *(const v4f*)&QPc[sl * 68 + j4 * 4];
                #pragma unroll
                for (int i = 0; i < 4; ++i) {
                    v4f k4 = *(const v4f*)&KPc[(tq * 4 + i) * 68 + j4 * 4];
                    s4[i] += q4[0]*k4[0] + q4[1]*k4[1] + q4[2]*k4[2] + q4[3]*k4[3];
                }
            }
            #pragma unroll
            for (int i = 0; i < 4; ++i) {
                int t = tq * 4 + i;
                Sl[sl * 36 + t] = (t <= sl) ? s4[i] : 0.f;
            }
        }
        __syncthreads();
        const int l = t256 & 31, dq = t256 >> 5;
        const int d0 = dq * 8;
        float acc[8] = {};
        for (int k = 0; k < 32; ++k) {
            float qc = QPc[l * 68 + k], qs = QPc[l * 68 + 32 + k];
            #pragma unroll
            for (int j4 = 0; j4 < 2; ++j4) {
                v4f pr = *(const v4f*)&PRl[k * 68 + d0 + j4 * 4];
                v4f pi = *(const v4f*)&PIl[k * 68 + d0 + j4 * 4];
                #pragma unroll
                for (int x = 0; x < 4; ++x)
                    acc[j4 * 4 + x] += qc * pr[x] + qs * pi[x];
            }
        }
        for (int t = 0; t < 32; ++t) {
            float s = Sl[l * 36 + t];
            #pragma unroll
            for (int j4 = 0; j4 < 2; ++j4) {
                v4f v4_ = *(const v4f*)&vall[t * 68 + d0 + j4 * 4];
                #pragma unroll
                for (int x = 0; x < 4; ++x)
                    acc[j4 * 4 + x] = fmaf(s, v4_[x], acc[j4 * 4 + x]);
            }
        }
        const int gl = c * 32 + l;
        const float inv = rsqrtf((float)((gl + 1) * 32));
        const size_t ob = ((size_t)(b * 2048 + gl)) * 256 + dh * 64 + d0;
        #pragma unroll
        for (int j4 = 0; j4 < 2; ++j4) {
            v4f v;
            #pragma unroll
            for (int x = 0; x < 4; ++x) v[x] = acc[j4 * 4 + x] * inv;
            *(v4f*)(out + ob + j4 * 4) = v;
        }
    }
}

// ---------------------------------------------------------------------------
extern "C" void kernel_launch(void* const* d_in, const int* in_sizes, int n_in,
                              void* d_out, int out_size, void* d_ws, size_t ws_size,
                              hipStream_t stream)
{
    const float* x   = (const float*)d_in[0];
    const float* kw1 = (const float*)d_in[1];
    const float* kb1 = (const float*)d_in[2];
    const float* kw2 = (const float*)d_in[3];
    const float* kb2 = (const float*)d_in[4];
    const float* qw1 = (const float*)d_in[5];
    const float* qb1 = (const float*)d_in[6];
    const float* qw2 = (const float*)d_in[7];
    const float* qb2 = (const float*)d_in[8];
    const float* vw  = (const float*)d_in[9];
    const float* vb  = (const float*)d_in[10];
    float* out = (float*)d_out;

    char* ws = (char*)d_ws;
    int*   bar = (int*)ws;   ws += 2048;
    float* KP  = (float*)ws; ws += (size_t)4096 * 64 * 4;
    float* QP  = (float*)ws; ws += (size_t)4096 * 64 * 4;
    bf16*  Wb  = (bf16*)ws;  ws += (size_t)768 * 256 * 2;
    bf16*  W2b = (bf16*)ws;  ws += (size_t)64 * 256 * 2;
    bf16*  Vb  = (bf16*)ws;  ws += (size_t)4096 * 256 * 2;
    bf16*  SRh = (bf16*)ws;  ws += (size_t)2 * 128 * 32 * 256 * 2;
    bf16*  SIh = (bf16*)ws;  ws += (size_t)2 * 128 * 32 * 256 * 2;
    bf16*  PFR = (bf16*)ws;  ws += (size_t)2 * 64 * 32 * 256 * 2;
    bf16*  PFI = (bf16*)ws;  ws += (size_t)2 * 64 * 32 * 256 * 2;

    hipMemsetAsync(bar, 0, 2048, stream);
    k_mega<<<256, 512, 0, stream>>>(x, kw1, kb1, kw2, kb2, qw1, qb1, qw2, qb2,
                                    vw, vb, KP, QP, Wb, W2b, Vb,
                                    SRh, SIh, PFR, PFI, out, bar);
}

// Round 11
// 87.466 us; speedup vs baseline: 1.1520x; 1.1520x over previous
//
#include <hip/hip_runtime.h>
#include <hip/hip_bf16.h>
#include <math.h>

typedef float v4f   __attribute__((ext_vector_type(4)));
typedef float f32x4 __attribute__((ext_vector_type(4)));
typedef short s16x8 __attribute__((ext_vector_type(8)));
typedef __hip_bfloat16 bf16;

#define PI_F 3.14159265358979323846f

// B=2, L=2048, D=256, K=32. Half-chunks: 16 rows, 128/batch (encode grain).
// Output chunks: 32 rows, 64/batch. PF = chunk-level exclusive prefix (bf16).
// One persistent kernel, NO grid barriers, NO threadfence: point-to-point
// flag DAG with LLC-coherent (sc0 sc1) stores for all cross-stage data.

__device__ inline unsigned short f2bf(float f) {
    unsigned int b = __float_as_uint(f);
    unsigned int r = (b + 0x7FFFu + ((b >> 16) & 1u)) >> 16;   // RNE
    return (unsigned short)r;
}
__device__ inline float bf2f(unsigned short u) {
    return __uint_as_float(((unsigned int)u) << 16);
}
__device__ inline void cvt8(const float* __restrict__ src, unsigned short* dst) {
    v4f a = *(const v4f*)src, b = *(const v4f*)(src + 4);
    ushort4 u0, u1;
    u0.x = f2bf(a[0]); u0.y = f2bf(a[1]); u0.z = f2bf(a[2]); u0.w = f2bf(a[3]);
    u1.x = f2bf(b[0]); u1.y = f2bf(b[1]); u1.z = f2bf(b[2]); u1.w = f2bf(b[3]);
    *(ushort4*)dst = u0; *(ushort4*)(dst + 4) = u1;
}
__device__ inline s16x8 pack_bf8(v4f w0, v4f w1) {
    s16x8 b;
    b[0] = (short)f2bf(w0[0]); b[1] = (short)f2bf(w0[1]);
    b[2] = (short)f2bf(w0[2]); b[3] = (short)f2bf(w0[3]);
    b[4] = (short)f2bf(w1[0]); b[5] = (short)f2bf(w1[1]);
    b[6] = (short)f2bf(w1[2]); b[7] = (short)f2bf(w1[3]);
    return b;
}

// LLC-coherent stores (write-through past the non-coherent per-XCD L2) —
// same cache bits the compiler emits for agent-scope atomics.
__device__ inline void st_sc32(void* p, unsigned int v) {
    asm volatile("global_store_dword %0, %1, off sc0 sc1" :: "v"(p), "v"(v) : "memory");
}
__device__ inline void st_sc16(void* p, unsigned int v) {
    asm volatile("global_store_short %0, %1, off sc0 sc1" :: "v"(p), "v"(v) : "memory");
}
__device__ inline void st_scf(float* p, float v) {
    asm volatile("global_store_dword %0, %1, off sc0 sc1" :: "v"(p), "v"(v) : "memory");
}
__device__ inline void flag_set(int* p, int v) {
    __hip_atomic_store(p, v, __ATOMIC_RELAXED, __HIP_MEMORY_SCOPE_AGENT);
}
__device__ inline int flag_get(const int* p) {
    return __hip_atomic_load(p, __ATOMIC_RELAXED, __HIP_MEMORY_SCOPE_AGENT);
}

__global__ __launch_bounds__(512) void k_mega(
    const float* __restrict__ X,
    const float* __restrict__ kw1, const float* __restrict__ kb1,
    const float* __restrict__ kw2, const float* __restrict__ kb2,
    const float* __restrict__ qw1, const float* __restrict__ qb1,
    const float* __restrict__ qw2, const float* __restrict__ qb2,
    const float* __restrict__ vw,  const float* __restrict__ vb,
    float* __restrict__ KP, float* __restrict__ QP,
    bf16* __restrict__ Vb,
    bf16* __restrict__ SRg, bf16* __restrict__ SIg,
    bf16* __restrict__ PFR, bf16* __restrict__ PFI,
    float* __restrict__ out, int* __restrict__ bar)
{
    __shared__ __align__(16) unsigned char smem[74240];
    const int tid = threadIdx.x, bid = blockIdx.x;
    int* encB  = bar;          // [256] one per half-chunk block
    int* prefC = bar + 256;    // [256] one per PF-scan block

    // ================= Stage B: encode one 16-row half-chunk ==============
    {
        unsigned short* Abf = (unsigned short*)smem;            // [16][264]
        unsigned short* Hkq = (unsigned short*)(smem + 8448);   // [16][520]
        unsigned short* Vt  = (unsigned short*)(smem + 25088);  // [256][40]
        unsigned short* CKc = (unsigned short*)(smem + 45568);  // [32][40]
        unsigned short* CKs = (unsigned short*)(smem + 48128);  // [32][40]
        const int lane = tid & 63, wid = tid >> 6;              // 8 waves
        const int lrow = lane & 15, lk8 = (lane >> 4) * 8, t0 = (lane >> 4) * 4;
        const int bb = bid >> 7, hc = bid & 127;
        const int row0 = bb * 2048 + hc * 16;

        {   // stage X tile (16x256 fp32 -> bf16 LDS); X constant -> plain loads
            int r = tid >> 5, c8 = (tid & 31) * 8;
            cvt8(X + (size_t)(row0 + r) * 256 + c8, &Abf[r * 264 + c8]);
        }
        {   // zero t=16..31 pads (GEMM3 runs K=32 over 16 real t rows)
            s16x8 z = {};
            { int r = tid >> 1, h = tid & 1; *(s16x8*)&Vt[r * 40 + 16 + h * 8] = z; }
            if (tid < 64)       { int r = tid >> 1, h = tid & 1;
                                  *(s16x8*)&CKc[r * 40 + 16 + h * 8] = z; }
            else if (tid < 128) { int r = (tid - 64) >> 1, h = tid & 1;
                                  *(s16x8*)&CKs[r * 40 + 16 + h * 8] = z; }
        }
        __syncthreads();

        // ---- GEMM1: wave owns 96 cols; fp32 weights cvt'd on the fly ----
        const int nb = wid * 96;
        const float* wrow[6];
        #pragma unroll
        for (int nf = 0; nf < 6; ++nf) {
            int n = nb + nf * 16 + lrow;
            wrow[nf] = (n < 256) ? kw1 + (size_t)n * 256
                     : (n < 512) ? qw1 + (size_t)(n - 256) * 256
                                 : vw  + (size_t)(n - 512) * 256;
        }
        f32x4 acc[6] = {};
        for (int k0 = 0; k0 < 256; k0 += 32) {
            s16x8 a = *(const s16x8*)&Abf[lrow * 264 + k0 + lk8];
            #pragma unroll
            for (int nf = 0; nf < 6; ++nf) {
                v4f w0 = *(const v4f*)(wrow[nf] + k0 + lk8);
                v4f w1 = *(const v4f*)(wrow[nf] + k0 + lk8 + 4);
                acc[nf] = __builtin_amdgcn_mfma_f32_16x16x32_bf16(
                    a, pack_bf8(w0, w1), acc[nf], 0, 0, 0);
            }
        }
        // ---- epilogue: Hkq (tanh, bf16 LDS) / Vt (LDS) + Vb (global sc1) ----
        #pragma unroll
        for (int nf = 0; nf < 6; ++nf) {
            int n = nb + nf * 16 + lrow;
            float bias = (n < 256) ? kb1[n] : (n < 512) ? qb1[n - 256] : vb[n - 512];
            if (n < 512) {
                #pragma unroll
                for (int r = 0; r < 4; ++r)
                    Hkq[(t0 + r) * 520 + n] = f2bf(tanhf(acc[nf][r] + bias));
            } else {
                int d = n - 512;
                ushort4 u;
                u.x = f2bf(acc[nf][0] + bias); u.y = f2bf(acc[nf][1] + bias);
                u.z = f2bf(acc[nf][2] + bias); u.w = f2bf(acc[nf][3] + bias);
                *(ushort4*)&Vt[d * 40 + t0] = u;
                unsigned short* Vg = (unsigned short*)Vb + (size_t)(row0 + t0) * 256 + d;
                st_sc16(Vg,       u.x); st_sc16(Vg + 256, u.y);
                st_sc16(Vg + 512, u.z); st_sc16(Vg + 768, u.w);
            }
        }
        __syncthreads();

        // ---- GEMM2 (waves 0-3): layer-2 + trig -> KP/QP (sc1), CK LDS ----
        if (wid < 4) {
            const int which = wid >> 1, nf = wid & 1;
            const float* W2row = (which ? qw2 : kw2) + (size_t)(nf * 16 + lrow) * 256;
            f32x4 u = {};
            for (int k0 = 0; k0 < 256; k0 += 32) {
                s16x8 a = *(const s16x8*)&Hkq[lrow * 520 + which * 256 + k0 + lk8];
                v4f w0 = *(const v4f*)(W2row + k0 + lk8);
                v4f w1 = *(const v4f*)(W2row + k0 + lk8 + 4);
                u = __builtin_amdgcn_mfma_f32_16x16x32_bf16(
                    a, pack_bf8(w0, w1), u, 0, 0, 0);
            }
            const int outk = nf * 16 + lrow;
            const float bias = (which ? qb2 : kb2)[outk];
            float* dst = which ? QP : KP;
            float cs[4], sn[4];
            #pragma unroll
            for (int r = 0; r < 4; ++r) {
                float ph = tanhf(u[r] + bias) * PI_F;
                __sincosf(ph, &sn[r], &cs[r]);
                int row = row0 + t0 + r;
                st_scf(&dst[(size_t)row * 64 + outk],      cs[r]);
                st_scf(&dst[(size_t)row * 64 + 32 + outk], sn[r]);
            }
            if (which == 0) {
                ushort4 uc, us;
                uc.x = f2bf(cs[0]); uc.y = f2bf(cs[1]); uc.z = f2bf(cs[2]); uc.w = f2bf(cs[3]);
                us.x = f2bf(sn[0]); us.y = f2bf(sn[1]); us.z = f2bf(sn[2]); us.w = f2bf(sn[3]);
                *(ushort4*)&CKc[outk * 40 + t0] = uc;
                *(ushort4*)&CKs[outk * 40 + t0] = us;
            }
        }
        __syncthreads();

        // ---- GEMM3 (all 8 waves): half-chunk sums -> SRh/SIh (sc1) ----
        {
            s16x8 ac0 = *(const s16x8*)&CKc[lrow * 40 + lk8];
            s16x8 ac1 = *(const s16x8*)&CKc[(16 + lrow) * 40 + lk8];
            s16x8 as0 = *(const s16x8*)&CKs[lrow * 40 + lk8];
            s16x8 as1 = *(const s16x8*)&CKs[(16 + lrow) * 40 + lk8];
            f32x4 zz = {};
            unsigned short* SRu = (unsigned short*)SRg;
            unsigned short* SIu = (unsigned short*)SIg;
            #pragma unroll
            for (int nf = 0; nf < 2; ++nf) {
                int dcol = wid * 32 + nf * 16 + lrow;
                s16x8 bv = *(const s16x8*)&Vt[dcol * 40 + lk8];
                f32x4 r0 = __builtin_amdgcn_mfma_f32_16x16x32_bf16(ac0, bv, zz, 0, 0, 0);
                f32x4 r1 = __builtin_amdgcn_mfma_f32_16x16x32_bf16(ac1, bv, zz, 0, 0, 0);
                f32x4 i0 = __builtin_amdgcn_mfma_f32_16x16x32_bf16(as0, bv, zz, 0, 0, 0);
                f32x4 i1 = __builtin_amdgcn_mfma_f32_16x16x32_bf16(as1, bv, zz, 0, 0, 0);
                size_t base = (((size_t)(bid)) * 32) * 256 + dcol;   // bid == b*128+hc
                #pragma unroll
                for (int r = 0; r < 4; ++r) {
                    int ka = t0 + r, kb_ = 16 + t0 + r;
                    st_sc16(SRu + base + (size_t)ka  * 256, f2bf(r0[r]));
                    st_sc16(SRu + base + (size_t)kb_ * 256, f2bf(r1[r]));
                    st_sc16(SIu + base + (size_t)ka  * 256, f2bf(i0[r]));
                    st_sc16(SIu + base + (size_t)kb_ * 256, f2bf(i1[r]));
                }
            }
        }
        asm volatile("s_waitcnt vmcnt(0)" ::: "memory");   // drain sc1 stores
        __syncthreads();                                    // all waves drained
        if (tid == 0) flag_set(&encB[bid], 1);              // publish
    }

    // ================= Stage C: PF scan slice (flag-gated) ================
    {
        const int b = bid >> 7, ri = (bid >> 6) & 1, seg = (bid >> 3) & 7, e2hi = bid & 7;
        const int need = 16 * (seg + 1);
        if (tid < 64) {
            for (;;) {
                int ok = 1;
                for (int h = tid; h < need; h += 64)
                    ok &= (flag_get(&encB[b * 128 + h]) != 0);
                if (__all(ok)) break;
                __builtin_amdgcn_s_sleep(2);
            }
        }
        __syncthreads();
        const unsigned short* S = (const unsigned short*)(ri ? SIg : SRg);
        unsigned short* PF = (unsigned short*)(ri ? PFI : PFR);
        const int e2 = e2hi * 512 + tid;
        const size_t col = (size_t)e2 * 2;
        const size_t hbase = (size_t)(b * 128) * 8192 + col;
        float r0 = 0.f, r1 = 0.f;
        for (int hp = 0; hp < seg * 16; ++hp) {
            ushort2 u = *(const ushort2*)(S + hbase + (size_t)hp * 8192);
            r0 += bf2f(u.x); r1 += bf2f(u.y);
        }
        #pragma unroll
        for (int j = 0; j < 8; ++j) {
            int c = seg * 8 + j;
            unsigned int w = (unsigned int)f2bf(r0) | ((unsigned int)f2bf(r1) << 16);
            st_sc32(PF + (size_t)(b * 64 + c) * 8192 + col, w);
            ushort2 u0 = *(const ushort2*)(S + hbase + (size_t)(2 * c)     * 8192);
            ushort2 u1 = *(const ushort2*)(S + hbase + (size_t)(2 * c + 1) * 8192);
            r0 += bf2f(u0.x) + bf2f(u1.x);
            r1 += bf2f(u0.y) + bf2f(u1.y);
        }
        asm volatile("s_waitcnt vmcnt(0)" ::: "memory");
        __syncthreads();
        if (tid == 0) flag_set(&prefC[bid], 1);
    }

    // ================= Stage D: output (flag-gated) =======================
    {
        const int b = bid >> 7, c = (bid >> 1) & 63, dhh = bid & 1;
        if (tid < 64) {
            for (;;) {
                int ok = 1;
                if (tid < 16) {
                    int ri = tid >> 3, e = tid & 7;
                    ok = (flag_get(&prefC[(b << 7) | (ri << 6) | ((c >> 3) << 3) | e]) != 0);
                } else if (tid < 18) {
                    ok = (flag_get(&encB[b * 128 + 2 * c + (tid - 16)]) != 0);
                }
                if (__all(ok)) break;
                __builtin_amdgcn_s_sleep(2);
            }
        }
        __syncthreads();

        float* sm  = (float*)smem;
        float* QPc = sm;                         // [32][68] (dup-written)
        float* KPc = sm + 2176;
        float* Sl  = sm + 4352;                  // [32][36]
        const int group = tid >> 8, t256 = tid & 255;
        float* grp  = sm + 5504 + group * 6528;
        float* vall = grp;                       // [32][68]
        float* PRl  = grp + 2176;
        float* PIl  = grp + 4352;
        const int dh = dhh * 2 + group;
        const int row0 = b * 2048 + c * 32;

        #pragma unroll
        for (int it = 0; it < 2; ++it) {
            int idx = t256 + it * 256, t = idx >> 4, j4 = idx & 15;
            *(v4f*)&QPc[t * 68 + j4 * 4] = *(const v4f*)(QP + (size_t)(row0 + t) * 64 + j4 * 4);
            *(v4f*)&KPc[t * 68 + j4 * 4] = *(const v4f*)(KP + (size_t)(row0 + t) * 64 + j4 * 4);
        }
        {   // V slice bf16 -> fp32 LDS
            int t = t256 >> 3, e8 = (t256 & 7) * 8;
            s16x8 u = *(const s16x8*)((const unsigned short*)Vb
                                      + (size_t)(row0 + t) * 256 + dh * 64 + e8);
            #pragma unroll
            for (int j = 0; j < 8; ++j) vall[t * 68 + e8 + j] = bf2f((unsigned short)u[j]);
        }
        {   // prefix state: direct PF read
            int k = t256 >> 3, dg = t256 & 7;
            size_t pb = ((size_t)(b * 64 + c)) * 8192 + k * 256 + dh * 64 + dg * 8;
            s16x8 ur = *(const s16x8*)((const unsigned short*)PFR + pb);
            s16x8 ui = *(const s16x8*)((const unsigned short*)PFI + pb);
            #pragma unroll
            for (int j = 0; j < 8; ++j) {
                PRl[k * 68 + dg * 8 + j] = bf2f((unsigned short)ur[j]);
                PIl[k * 68 + dg * 8 + j] = bf2f((unsigned short)ui[j]);
            }
        }
        __syncthreads();
        {   // S tile (32x32 causal) — both groups compute identical values
            const int sl = t256 >> 3, tq = t256 & 7;
            float s4[4] = {0.f, 0.f, 0.f, 0.f};
            for (int j4 = 0; j4 < 16; ++j4) {
                v4f q4 = *(const v4f*)&QPc[sl * 68 + j4 * 4];
                #pragma unroll
                for (int i = 0; i < 4; ++i) {
                    v4f k4 = *(const v4f*)&KPc[(tq * 4 + i) * 68 + j4 * 4];
                    s4[i] += q4[0]*k4[0] + q4[1]*k4[1] + q4[2]*k4[2] + q4[3]*k4[3];
                }
            }
            #pragma unroll
            for (int i = 0; i < 4; ++i) {
                int t = tq * 4 + i;
                Sl[sl * 36 + t] = (t <= sl) ? s4[i] : 0.f;
            }
        }
        __syncthreads();
        const int l = t256 & 31, dq = t256 >> 5;
        const int d0 = dq * 8;
        float acc[8] = {};
        for (int k = 0; k < 32; ++k) {
            float qc = QPc[l * 68 + k], qs = QPc[l * 68 + 32 + k];
            #pragma unroll
            for (int j4 = 0; j4 < 2; ++j4) {
                v4f pr = *(const v4f*)&PRl[k * 68 + d0 + j4 * 4];
                v4f pi = *(const v4f*)&PIl[k * 68 + d0 + j4 * 4];
                #pragma unroll
                for (int x = 0; x < 4; ++x)
                    acc[j4 * 4 + x] += qc * pr[x] + qs * pi[x];
            }
        }
        for (int t = 0; t < 32; ++t) {
            float s = Sl[l * 36 + t];
            #pragma unroll
            for (int j4 = 0; j4 < 2; ++j4) {
                v4f v4_ = *(const v4f*)&vall[t * 68 + d0 + j4 * 4];
                #pragma unroll
                for (int x = 0; x < 4; ++x)
                    acc[j4 * 4 + x] = fmaf(s, v4_[x], acc[j4 * 4 + x]);
            }
        }
        const int gl = c * 32 + l;
        const float inv = rsqrtf((float)((gl + 1) * 32));
        const size_t ob = ((size_t)(b * 2048 + gl)) * 256 + dh * 64 + d0;
        #pragma unroll
        for (int j4 = 0; j4 < 2; ++j4) {
            v4f v;
            #pragma unroll
            for (int x = 0; x < 4; ++x) v[x] = acc[j4 * 4 + x] * inv;
            *(v4f*)(out + ob + j4 * 4) = v;
        }
    }
}

// ---------------------------------------------------------------------------
extern "C" void kernel_launch(void* const* d_in, const int* in_sizes, int n_in,
                              void* d_out, int out_size, void* d_ws, size_t ws_size,
                              hipStream_t stream)
{
    const float* x   = (const float*)d_in[0];
    const float* kw1 = (const float*)d_in[1];
    const float* kb1 = (const float*)d_in[2];
    const float* kw2 = (const float*)d_in[3];
    const float* kb2 = (const float*)d_in[4];
    const float* qw1 = (const float*)d_in[5];
    const float* qb1 = (const float*)d_in[6];
    const float* qw2 = (const float*)d_in[7];
    const float* qb2 = (const float*)d_in[8];
    const float* vw  = (const float*)d_in[9];
    const float* vb  = (const float*)d_in[10];
    float* out = (float*)d_out;

    char* ws = (char*)d_ws;
    int*   bar = (int*)ws;   ws += 2048;
    float* KP  = (float*)ws; ws += (size_t)4096 * 64 * 4;
    float* QP  = (float*)ws; ws += (size_t)4096 * 64 * 4;
    bf16*  Vb  = (bf16*)ws;  ws += (size_t)4096 * 256 * 2;
    bf16*  SRh = (bf16*)ws;  ws += (size_t)2 * 128 * 32 * 256 * 2;
    bf16*  SIh = (bf16*)ws;  ws += (size_t)2 * 128 * 32 * 256 * 2;
    bf16*  PFR = (bf16*)ws;  ws += (size_t)2 * 64 * 32 * 256 * 2;
    bf16*  PFI = (bf16*)ws;  ws += (size_t)2 * 64 * 32 * 256 * 2;

    hipMemsetAsync(bar, 0, 2048, stream);
    k_mega<<<256, 512, 0, stream>>>(x, kw1, kb1, kw2, kb2, qw1, qb1, qw2, qb2,
                                    vw, vb, KP, QP, Vb, SRh, SIh, PFR, PFI,
                                    out, bar);
}

// Round 12
// 59.833 us; speedup vs baseline: 1.6841x; 1.4618x over previous
//
#include <hip/hip_runtime.h>
#include <hip/hip_bf16.h>
#include <math.h>

typedef float v4f   __attribute__((ext_vector_type(4)));
typedef float f32x4 __attribute__((ext_vector_type(4)));
typedef short s16x8 __attribute__((ext_vector_type(8)));
typedef __hip_bfloat16 bf16;

#define PI_F 3.14159265358979323846f

// B=2, L=2048, D=256, K=32. Chunks: 32 rows, 64/batch, 128 total.
// 2 dispatches: k_encode (fused MLP+trig+chunk-sums, weights cvt'd on the
// fly) -> k_attnout (inline exclusive-prefix walk over L2-resident chunk
// tiles + within-chunk causal part). Persistent-kernel path abandoned
// (R7-R11 post-mortems: barrier/fence/low-occupancy overheads structural).

__device__ inline unsigned short f2bf(float f) {
    unsigned int b = __float_as_uint(f);
    unsigned int r = (b + 0x7FFFu + ((b >> 16) & 1u)) >> 16;   // RNE
    return (unsigned short)r;
}
__device__ inline float bf2f(unsigned short u) {
    return __uint_as_float(((unsigned int)u) << 16);
}
__device__ inline void cvt8(const float* __restrict__ src, unsigned short* dst) {
    v4f a = *(const v4f*)src, b = *(const v4f*)(src + 4);
    ushort4 u0, u1;
    u0.x = f2bf(a[0]); u0.y = f2bf(a[1]); u0.z = f2bf(a[2]); u0.w = f2bf(a[3]);
    u1.x = f2bf(b[0]); u1.y = f2bf(b[1]); u1.z = f2bf(b[2]); u1.w = f2bf(b[3]);
    *(ushort4*)dst = u0; *(ushort4*)(dst + 4) = u1;
}
__device__ inline s16x8 pack_bf8(const float* __restrict__ p) {
    v4f w0 = *(const v4f*)p, w1 = *(const v4f*)(p + 4);
    s16x8 b;
    b[0] = (short)f2bf(w0[0]); b[1] = (short)f2bf(w0[1]);
    b[2] = (short)f2bf(w0[2]); b[3] = (short)f2bf(w0[3]);
    b[4] = (short)f2bf(w1[0]); b[5] = (short)f2bf(w1[1]);
    b[6] = (short)f2bf(w1[2]); b[7] = (short)f2bf(w1[3]);
    return b;
}

// ---------------------------------------------------------------------------
// Kernel 1: fused encode + chunk-state. One block per (b, chunk): 128 blocks,
// 1024 threads (16 waves). LDS 58.9 KB (Abf region reused for Vt/CK).
// Proven R6 structure; weights converted fp32->bf16 in registers (no cvtw).
// ---------------------------------------------------------------------------
__global__ __launch_bounds__(1024) void k_encode(
    const float* __restrict__ X,
    const float* __restrict__ kw1, const float* __restrict__ kb1,
    const float* __restrict__ kw2, const float* __restrict__ kb2,
    const float* __restrict__ qw1, const float* __restrict__ qb1,
    const float* __restrict__ qw2, const float* __restrict__ qb2,
    const float* __restrict__ vw,  const float* __restrict__ vb,
    float* __restrict__ KP, float* __restrict__ QP,
    bf16* __restrict__ Vb, bf16* __restrict__ SRg, bf16* __restrict__ SIg)
{
    __shared__ __align__(16) unsigned char smem[58880];
    unsigned short* Abf = (unsigned short*)smem;            // 32x264 bf16 = 16896 B
    unsigned short* Vt  = (unsigned short*)smem;            // 256x40 = 20480 B (after GEMM1)
    unsigned short* CKc = (unsigned short*)(smem + 20480);  // 32x40 = 2560 B
    unsigned short* CKs = (unsigned short*)(smem + 23040);  // 32x40 = 2560 B
    unsigned short* Hkq = (unsigned short*)(smem + 25600);  // 32x520 = 33280 B

    const int tid  = threadIdx.x;
    const int lane = tid & 63, wid = tid >> 6;          // 16 waves
    const int lrow = lane & 15, lk8 = (lane >> 4) * 8;
    const int t0   = (lane >> 4) * 4;
    const int bb = blockIdx.x >> 6, cc = blockIdx.x & 63;
    const int row0 = bb * 2048 + cc * 32;

    // ---- 1) stage X tile (fp32 -> bf16 LDS) ----
    {
        int r = tid >> 5, c8 = (tid & 31) * 8;
        cvt8(X + (size_t)(row0 + r) * 256 + c8, &Abf[r * 264 + c8]);
    }
    __syncthreads();

    // ---- 2) GEMM1: wave owns cols nb..nb+47 (3 n-frags x 2 m-frags) ----
    const int nb = wid * 48;
    const float* wrow[3];
    float bias1[3];
    #pragma unroll
    for (int nf = 0; nf < 3; ++nf) {
        int n = nb + nf * 16 + lrow;
        wrow[nf]  = (n < 256) ? kw1 + (size_t)n * 256
                  : (n < 512) ? qw1 + (size_t)(n - 256) * 256
                              : vw  + (size_t)(n - 512) * 256;
        bias1[nf] = (n < 256) ? kb1[n] : (n < 512) ? qb1[n - 256] : vb[n - 512];
    }
    f32x4 acc[2][3] = {};
    for (int k0 = 0; k0 < 256; k0 += 32) {
        s16x8 a[2], b[3];
        #pragma unroll
        for (int mf = 0; mf < 2; ++mf)
            a[mf] = *(const s16x8*)&Abf[(mf * 16 + lrow) * 264 + k0 + lk8];
        #pragma unroll
        for (int nf = 0; nf < 3; ++nf)
            b[nf] = pack_bf8(wrow[nf] + k0 + lk8);
        #pragma unroll
        for (int mf = 0; mf < 2; ++mf)
            #pragma unroll
            for (int nf = 0; nf < 3; ++nf)
                acc[mf][nf] = __builtin_amdgcn_mfma_f32_16x16x32_bf16(
                    a[mf], b[nf], acc[mf][nf], 0, 0, 0);
    }
    __syncthreads();   // all A reads done before Abf region is reused as Vt

    // ---- 3) epilogue -> Hkq / Vt LDS (+ Vb global) ----
    #pragma unroll
    for (int nf = 0; nf < 3; ++nf) {
        int n = nb + nf * 16 + lrow;
        float bias = bias1[nf];
        #pragma unroll
        for (int mf = 0; mf < 2; ++mf) {
            int tb = mf * 16 + t0;
            if (n < 512) {
                #pragma unroll
                for (int r = 0; r < 4; ++r)
                    Hkq[(tb + r) * 520 + n] = f2bf(tanhf(acc[mf][nf][r] + bias));
            } else {
                int d = n - 512;
                float v0 = acc[mf][nf][0] + bias, v1 = acc[mf][nf][1] + bias;
                float v2 = acc[mf][nf][2] + bias, v3 = acc[mf][nf][3] + bias;
                ushort4 u;
                u.x = f2bf(v0); u.y = f2bf(v1); u.z = f2bf(v2); u.w = f2bf(v3);
                *(ushort4*)&Vt[d * 40 + tb] = u;
                unsigned short* Vg = (unsigned short*)Vb + (size_t)(row0 + tb) * 256 + d;
                Vg[0] = u.x; Vg[256] = u.y; Vg[512] = u.z; Vg[768] = u.w;
            }
        }
    }
    __syncthreads();

    // ---- 4) GEMM2 (waves 0-7): layer-2 + trig ----
    if (wid < 8) {
        const int which = wid >> 2;           // 0=K, 1=Q
        const int q = wid & 3, mf = q >> 1, nf = q & 1;
        const int hoff = which * 256;
        const float* W2row = (which ? qw2 : kw2) + (size_t)(nf * 16 + lrow) * 256;
        f32x4 u = {};
        for (int k0 = 0; k0 < 256; k0 += 32) {
            s16x8 a = *(const s16x8*)&Hkq[(mf * 16 + lrow) * 520 + hoff + k0 + lk8];
            u = __builtin_amdgcn_mfma_f32_16x16x32_bf16(
                a, pack_bf8(W2row + k0 + lk8), u, 0, 0, 0);
        }
        const int outk = nf * 16 + lrow;      // phase index 0..31
        const float bias = (which ? qb2 : kb2)[outk];
        float* dst = which ? QP : KP;
        float cs[4], sn[4];
        #pragma unroll
        for (int r = 0; r < 4; ++r) {
            float ph = tanhf(u[r] + bias) * PI_F;
            float s, c_;
            __sincosf(ph, &s, &c_);
            cs[r] = c_; sn[r] = s;
            int row = mf * 16 + t0 + r;
            dst[(size_t)(row0 + row) * 64 + outk]      = c_;
            dst[(size_t)(row0 + row) * 64 + 32 + outk] = s;
        }
        if (which == 0) {
            ushort4 uc, us;
            uc.x = f2bf(cs[0]); uc.y = f2bf(cs[1]); uc.z = f2bf(cs[2]); uc.w = f2bf(cs[3]);
            us.x = f2bf(sn[0]); us.y = f2bf(sn[1]); us.z = f2bf(sn[2]); us.w = f2bf(sn[3]);
            *(ushort4*)&CKc[outk * 40 + mf * 16 + t0] = uc;
            *(ushort4*)&CKs[outk * 40 + mf * 16 + t0] = us;
        }
    }
    __syncthreads();

    // ---- 5) GEMM3: chunk sums. wave wid owns d-block wid*16..+15 ----
    {
        s16x8 bV = *(const s16x8*)&Vt[(wid * 16 + lrow) * 40 + lk8];
        s16x8 c0 = *(const s16x8*)&CKc[(lrow) * 40 + lk8];
        s16x8 c1 = *(const s16x8*)&CKc[(16 + lrow) * 40 + lk8];
        s16x8 s0 = *(const s16x8*)&CKs[(lrow) * 40 + lk8];
        s16x8 s1 = *(const s16x8*)&CKs[(16 + lrow) * 40 + lk8];
        f32x4 z = {};
        f32x4 r0 = __builtin_amdgcn_mfma_f32_16x16x32_bf16(c0, bV, z, 0, 0, 0);
        f32x4 r1 = __builtin_amdgcn_mfma_f32_16x16x32_bf16(c1, bV, z, 0, 0, 0);
        f32x4 i0 = __builtin_amdgcn_mfma_f32_16x16x32_bf16(s0, bV, z, 0, 0, 0);
        f32x4 i1 = __builtin_amdgcn_mfma_f32_16x16x32_bf16(s1, bV, z, 0, 0, 0);
        const int d = wid * 16 + lrow;
        size_t base = (((size_t)(bb * 64 + cc)) * 32) * 256 + d;
        unsigned short* SRu = (unsigned short*)SRg;
        unsigned short* SIu = (unsigned short*)SIg;
        #pragma unroll
        for (int r = 0; r < 4; ++r) {
            int ka = t0 + r, kb_ = 16 + t0 + r;
            SRu[base + (size_t)ka  * 256] = f2bf(r0[r]);
            SRu[base + (size_t)kb_ * 256] = f2bf(r1[r]);
            SIu[base + (size_t)ka  * 256] = f2bf(i0[r]);
            SIu[base + (size_t)kb_ * 256] = f2bf(i1[r]);
        }
    }
}

// ---------------------------------------------------------------------------
// Kernel 2: output. grid (128, 4): x = b*64+c, y = d-quarter (64 cols).
// Exclusive prefix rebuilt inline by walking ALL prior chunk tiles (bf16,
// L2/LLC-resident: 4 MB total; <=63 x 16 B loads per thread, ~0.6us avg).
// ---------------------------------------------------------------------------
__global__ __launch_bounds__(256) void k_attnout(
    const float* __restrict__ KP, const float* __restrict__ QP,
    const bf16* __restrict__ Vb,
    const bf16* __restrict__ SRg, const bf16* __restrict__ SIg,
    float* __restrict__ out)
{
    __shared__ float QPc[32 * 68], KPc[32 * 68], Sl[32 * 36];
    __shared__ float vall[32 * 68], PRl[32 * 68], PIl[32 * 68];
    const int tid = threadIdx.x;
    const int b = blockIdx.x >> 6, c = blockIdx.x & 63;
    const int dh = blockIdx.y;
    const int row0 = b * 2048 + c * 32;

    #pragma unroll
    for (int it = 0; it < 2; ++it) {
        int idx = tid + it * 256, t = idx >> 4, j4 = idx & 15;
        *(v4f*)&QPc[t * 68 + j4 * 4] = *(const v4f*)(QP + (size_t)(row0 + t) * 64 + j4 * 4);
        *(v4f*)&KPc[t * 68 + j4 * 4] = *(const v4f*)(KP + (size_t)(row0 + t) * 64 + j4 * 4);
    }
    {   // V slice bf16 -> fp32 LDS
        int t = tid >> 3, e8 = (tid & 7) * 8;
        s16x8 u = *(const s16x8*)((const unsigned short*)Vb
                                  + (size_t)(row0 + t) * 256 + dh * 64 + e8);
        #pragma unroll
        for (int j = 0; j < 8; ++j) vall[t * 68 + e8 + j] = bf2f((unsigned short)u[j]);
    }
    {   // exclusive-prefix: walk all prior chunk tiles
        int k = tid >> 3, dg = tid & 7;
        float pr[8] = {}, pi[8] = {};
        const unsigned short* SRu = (const unsigned short*)SRg;
        const unsigned short* SIu = (const unsigned short*)SIg;
        size_t sb = ((size_t)(b * 64) * 32 + k) * 256 + dh * 64 + dg * 8;
        #pragma unroll 4
        for (int cp = 0; cp < c; ++cp) {
            s16x8 ur = *(const s16x8*)(SRu + sb + (size_t)cp * 8192);
            s16x8 ui = *(const s16x8*)(SIu + sb + (size_t)cp * 8192);
            #pragma unroll
            for (int j = 0; j < 8; ++j) {
                pr[j] += bf2f((unsigned short)ur[j]);
                pi[j] += bf2f((unsigned short)ui[j]);
            }
        }
        #pragma unroll
        for (int j = 0; j < 8; ++j) {
            PRl[k * 68 + dg * 8 + j] = pr[j];
            PIl[k * 68 + dg * 8 + j] = pi[j];
        }
    }
    __syncthreads();
    {   // S tile (32x32, causal-masked)
        const int sl = tid >> 3, tq = tid & 7;
        float s4[4] = {0.f, 0.f, 0.f, 0.f};
        for (int j4 = 0; j4 < 16; ++j4) {
            v4f q4 = *(const v4f*)&QPc[sl * 68 + j4 * 4];
            #pragma unroll
            for (int i = 0; i < 4; ++i) {
                v4f k4 = *(const v4f*)&KPc[(tq * 4 + i) * 68 + j4 * 4];
                s4[i] += q4[0]*k4[0] + q4[1]*k4[1] + q4[2]*k4[2] + q4[3]*k4[3];
            }
        }
        #pragma unroll
        for (int i = 0; i < 4; ++i) {
            int t = tq * 4 + i;
            Sl[sl * 36 + t] = (t <= sl) ? s4[i] : 0.f;
        }
    }
    __syncthreads();
    const int l = tid & 31, dq = tid >> 5;
    const int d0 = dq * 8;
    float acc[8] = {};
    for (int k = 0; k < 32; ++k) {
        float qc = QPc[l * 68 + k], qs = QPc[l * 68 + 32 + k];
        #pragma unroll
        for (int j4 = 0; j4 < 2; ++j4) {
            v4f pr = *(const v4f*)&PRl[k * 68 + d0 + j4 * 4];
            v4f pi = *(const v4f*)&PIl[k * 68 + d0 + j4 * 4];
            #pragma unroll
            for (int x = 0; x < 4; ++x)
                acc[j4 * 4 + x] += qc * pr[x] + qs * pi[x];
        }
    }
    for (int t = 0; t < 32; ++t) {
        float s = Sl[l * 36 + t];
        #pragma unroll
        for (int j4 = 0; j4 < 2; ++j4) {
            v4f v4_ = *(const v4f*)&vall[t * 68 + d0 + j4 * 4];
            #pragma unroll
            for (int x = 0; x < 4; ++x)
                acc[j4 * 4 + x] = fmaf(s, v4_[x], acc[j4 * 4 + x]);
        }
    }
    const int gl = c * 32 + l;
    const float inv = rsqrtf((float)((gl + 1) * 32));
    const size_t ob = ((size_t)(b * 2048 + gl)) * 256 + dh * 64 + d0;
    #pragma unroll
    for (int j4 = 0; j4 < 2; ++j4) {
        v4f v;
        #pragma unroll
        for (int x = 0; x < 4; ++x) v[x] = acc[j4 * 4 + x] * inv;
        *(v4f*)(out + ob + j4 * 4) = v;
    }
}

// ---------------------------------------------------------------------------
extern "C" void kernel_launch(void* const* d_in, const int* in_sizes, int n_in,
                              void* d_out, int out_size, void* d_ws, size_t ws_size,
                              hipStream_t stream)
{
    const float* x   = (const float*)d_in[0];
    const float* kw1 = (const float*)d_in[1];
    const float* kb1 = (const float*)d_in[2];
    const float* kw2 = (const float*)d_in[3];
    const float* kb2 = (const float*)d_in[4];
    const float* qw1 = (const float*)d_in[5];
    const float* qb1 = (const float*)d_in[6];
    const float* qw2 = (const float*)d_in[7];
    const float* qb2 = (const float*)d_in[8];
    const float* vw  = (const float*)d_in[9];
    const float* vb  = (const float*)d_in[10];
    float* out = (float*)d_out;

    char* ws = (char*)d_ws;
    float* KP = (float*)ws; ws += (size_t)4096 * 64 * 4;
    float* QP = (float*)ws; ws += (size_t)4096 * 64 * 4;
    bf16*  Vb = (bf16*)ws;  ws += (size_t)4096 * 256 * 2;
    bf16*  SR = (bf16*)ws;  ws += (size_t)2 * 64 * 32 * 256 * 2;
    bf16*  SI = (bf16*)ws;  ws += (size_t)2 * 64 * 32 * 256 * 2;

    k_encode <<<128,          1024, 0, stream>>>(x, kw1, kb1, kw2, kb2,
                                                 qw1, qb1, qw2, qb2, vw, vb,
                                                 KP, QP, Vb, SR, SI);
    k_attnout<<<dim3(128, 4), 256,  0, stream>>>(KP, QP, Vb, SR, SI, out);
}

// Round 13
// 52.969 us; speedup vs baseline: 1.9023x; 1.1296x over previous
//
#include <hip/hip_runtime.h>
#include <hip/hip_bf16.h>
#include <math.h>

typedef float v4f   __attribute__((ext_vector_type(4)));
typedef float f32x4 __attribute__((ext_vector_type(4)));
typedef short s16x8 __attribute__((ext_vector_type(8)));
typedef __hip_bfloat16 bf16;

#define PI_F 3.14159265358979323846f

// B=2, L=2048, D=256, K=32. Chunks: 32 rows, 64/batch, 128 total.
// 3 dispatches (priced via R2/R6/R9/R12 cross-round data):
//   cvtw    — pre-convert weights to bf16 ONCE (on-the-fly cvt costs 2x L1
//             bytes + pack VALU in every encode block: R12 regression)
//   fused1  — R6's proven 32-row-chunk encode (bf16 weight loads)
//   attnout — R12's proven full prefix-walk (scanpart dispatch not worth it)

__device__ inline unsigned short f2bf(float f) {
    unsigned int b = __float_as_uint(f);
    unsigned int r = (b + 0x7FFFu + ((b >> 16) & 1u)) >> 16;   // RNE
    return (unsigned short)r;
}
__device__ inline float bf2f(unsigned short u) {
    return __uint_as_float(((unsigned int)u) << 16);
}
__device__ inline void cvt8(const float* __restrict__ src, unsigned short* dst) {
    v4f a = *(const v4f*)src, b = *(const v4f*)(src + 4);
    ushort4 u0, u1;
    u0.x = f2bf(a[0]); u0.y = f2bf(a[1]); u0.z = f2bf(a[2]); u0.w = f2bf(a[3]);
    u1.x = f2bf(b[0]); u1.y = f2bf(b[1]); u1.z = f2bf(b[2]); u1.w = f2bf(b[3]);
    *(ushort4*)dst = u0; *(ushort4*)(dst + 4) = u1;
}

// ---------------------------------------------------------------------------
// Kernel A: one-time weight conversion (R6 verbatim).
// Wb[768][256] = [kw1|qw1|vw] bf16 ; W2b[64][256] = [kw2|qw2] bf16.
// ---------------------------------------------------------------------------
__global__ __launch_bounds__(256) void k_cvtw(
    const float* __restrict__ kw1, const float* __restrict__ qw1,
    const float* __restrict__ vw,  const float* __restrict__ kw2,
    const float* __restrict__ qw2, bf16* __restrict__ Wb, bf16* __restrict__ W2b)
{
    int i8 = blockIdx.x * 256 + threadIdx.x;
    int r = i8 >> 5, c8 = (i8 & 31) * 8;
    const float* src;
    unsigned short* dst;
    if (r < 768) {
        src = (r < 256) ? kw1 + (size_t)r * 256
            : (r < 512) ? qw1 + (size_t)(r - 256) * 256
                        : vw  + (size_t)(r - 512) * 256;
        dst = (unsigned short*)Wb + (size_t)r * 256;
    } else {
        int r2 = r - 768;
        src = (r2 < 32) ? kw2 + (size_t)r2 * 256 : qw2 + (size_t)(r2 - 32) * 256;
        dst = (unsigned short*)W2b + (size_t)r2 * 256;
    }
    cvt8(src + c8, dst + c8);
}

// ---------------------------------------------------------------------------
// Kernel B: fused encode + chunk-state (R6 verbatim). One block per (b,chunk):
// 128 blocks, 1024 threads (16 waves). LDS 58.9 KB (Abf reused as Vt/CK).
// ---------------------------------------------------------------------------
__global__ __launch_bounds__(1024) void k_fused1(
    const float* __restrict__ X,   const bf16* __restrict__ Wbk,
    const float* __restrict__ kb1, const float* __restrict__ qb1,
    const float* __restrict__ vb,  const bf16* __restrict__ W2bk,
    const float* __restrict__ kb2, const float* __restrict__ qb2,
    float* __restrict__ KP, float* __restrict__ QP,
    bf16* __restrict__ Vb, bf16* __restrict__ SRg, bf16* __restrict__ SIg)
{
    __shared__ __align__(16) unsigned char smem[58880];
    unsigned short* Abf = (unsigned short*)smem;            // 32x264 bf16 = 16896 B
    unsigned short* Vt  = (unsigned short*)smem;            // 256x40 = 20480 B (after GEMM1)
    unsigned short* CKc = (unsigned short*)(smem + 20480);  // 32x40 = 2560 B
    unsigned short* CKs = (unsigned short*)(smem + 23040);  // 32x40 = 2560 B
    unsigned short* Hkq = (unsigned short*)(smem + 25600);  // 32x520 = 33280 B

    const int tid  = threadIdx.x;
    const int lane = tid & 63, wid = tid >> 6;          // 16 waves
    const int lrow = lane & 15, lk8 = (lane >> 4) * 8;
    const int t0   = (lane >> 4) * 4;
    const int bb = blockIdx.x >> 6, cc = blockIdx.x & 63;
    const int row0 = bb * 2048 + cc * 32;

    // ---- 1) stage X tile (fp32 -> bf16 LDS) ----
    {
        int r = tid >> 5, c8 = (tid & 31) * 8;
        cvt8(X + (size_t)(row0 + r) * 256 + c8, &Abf[r * 264 + c8]);
    }
    __syncthreads();

    // ---- 2) GEMM1: wave owns cols nb..nb+47 (3 n-frags x 2 m-frags) ----
    const int nb = wid * 48;
    const unsigned short* Wu = (const unsigned short*)Wbk;
    f32x4 acc[2][3] = {};
    for (int k0 = 0; k0 < 256; k0 += 32) {
        s16x8 a[2], b[3];
        #pragma unroll
        for (int mf = 0; mf < 2; ++mf)
            a[mf] = *(const s16x8*)&Abf[(mf * 16 + lrow) * 264 + k0 + lk8];
        #pragma unroll
        for (int nf = 0; nf < 3; ++nf)
            b[nf] = *(const s16x8*)(Wu + (size_t)(nb + nf * 16 + lrow) * 256 + k0 + lk8);
        #pragma unroll
        for (int mf = 0; mf < 2; ++mf)
            #pragma unroll
            for (int nf = 0; nf < 3; ++nf)
                acc[mf][nf] = __builtin_amdgcn_mfma_f32_16x16x32_bf16(
                    a[mf], b[nf], acc[mf][nf], 0, 0, 0);
    }
    __syncthreads();   // all A reads done before Abf region is reused as Vt

    // ---- 3) epilogue -> Hkq / Vt LDS (+ Vb global) ----
    #pragma unroll
    for (int nf = 0; nf < 3; ++nf) {
        int n = nb + nf * 16 + lrow;
        float bias = (n < 256) ? kb1[n] : (n < 512) ? qb1[n - 256] : vb[n - 512];
        #pragma unroll
        for (int mf = 0; mf < 2; ++mf) {
            int tb = mf * 16 + t0;
            if (n < 512) {
                #pragma unroll
                for (int r = 0; r < 4; ++r)
                    Hkq[(tb + r) * 520 + n] = f2bf(tanhf(acc[mf][nf][r] + bias));
            } else {
                int d = n - 512;
                float v0 = acc[mf][nf][0] + bias, v1 = acc[mf][nf][1] + bias;
                float v2 = acc[mf][nf][2] + bias, v3 = acc[mf][nf][3] + bias;
                ushort4 u;
                u.x = f2bf(v0); u.y = f2bf(v1); u.z = f2bf(v2); u.w = f2bf(v3);
                *(ushort4*)&Vt[d * 40 + tb] = u;
                unsigned short* Vg = (unsigned short*)Vb + (size_t)(row0 + tb) * 256 + d;
                Vg[0] = u.x; Vg[256] = u.y; Vg[512] = u.z; Vg[768] = u.w;
            }
        }
    }
    __syncthreads();

    // ---- 4) GEMM2 (waves 0-7): layer-2 + trig ----
    if (wid < 8) {
        const int which = wid >> 2;           // 0=K, 1=Q
        const int q = wid & 3, mf = q >> 1, nf = q & 1;
        const int hoff = which * 256;
        const unsigned short* W2u =
            (const unsigned short*)W2bk + (size_t)(which * 32 + nf * 16 + lrow) * 256;
        f32x4 u = {};
        for (int k0 = 0; k0 < 256; k0 += 32) {
            s16x8 a = *(const s16x8*)&Hkq[(mf * 16 + lrow) * 520 + hoff + k0 + lk8];
            s16x8 b = *(const s16x8*)(W2u + k0 + lk8);
            u = __builtin_amdgcn_mfma_f32_16x16x32_bf16(a, b, u, 0, 0, 0);
        }
        const int outk = nf * 16 + lrow;      // phase index 0..31
        const float bias = (which ? qb2 : kb2)[outk];
        float* dst = which ? QP : KP;
        float cs[4], sn[4];
        #pragma unroll
        for (int r = 0; r < 4; ++r) {
            float ph = tanhf(u[r] + bias) * PI_F;
            float s, c_;
            __sincosf(ph, &s, &c_);
            cs[r] = c_; sn[r] = s;
            int row = mf * 16 + t0 + r;
            dst[(size_t)(row0 + row) * 64 + outk]      = c_;
            dst[(size_t)(row0 + row) * 64 + 32 + outk] = s;
        }
        if (which == 0) {
            ushort4 uc, us;
            uc.x = f2bf(cs[0]); uc.y = f2bf(cs[1]); uc.z = f2bf(cs[2]); uc.w = f2bf(cs[3]);
            us.x = f2bf(sn[0]); us.y = f2bf(sn[1]); us.z = f2bf(sn[2]); us.w = f2bf(sn[3]);
            *(ushort4*)&CKc[outk * 40 + mf * 16 + t0] = uc;
            *(ushort4*)&CKs[outk * 40 + mf * 16 + t0] = us;
        }
    }
    __syncthreads();

    // ---- 5) GEMM3: chunk sums. wave wid owns d-block wid*16..+15 ----
    {
        s16x8 bV = *(const s16x8*)&Vt[(wid * 16 + lrow) * 40 + lk8];
        s16x8 c0 = *(const s16x8*)&CKc[(lrow) * 40 + lk8];
        s16x8 c1 = *(const s16x8*)&CKc[(16 + lrow) * 40 + lk8];
        s16x8 s0 = *(const s16x8*)&CKs[(lrow) * 40 + lk8];
        s16x8 s1 = *(const s16x8*)&CKs[(16 + lrow) * 40 + lk8];
        f32x4 z = {};
        f32x4 r0 = __builtin_amdgcn_mfma_f32_16x16x32_bf16(c0, bV, z, 0, 0, 0);
        f32x4 r1 = __builtin_amdgcn_mfma_f32_16x16x32_bf16(c1, bV, z, 0, 0, 0);
        f32x4 i0 = __builtin_amdgcn_mfma_f32_16x16x32_bf16(s0, bV, z, 0, 0, 0);
        f32x4 i1 = __builtin_amdgcn_mfma_f32_16x16x32_bf16(s1, bV, z, 0, 0, 0);
        const int d = wid * 16 + lrow;
        size_t base = (((size_t)(bb * 64 + cc)) * 32) * 256 + d;
        unsigned short* SRu = (unsigned short*)SRg;
        unsigned short* SIu = (unsigned short*)SIg;
        #pragma unroll
        for (int r = 0; r < 4; ++r) {
            int ka = t0 + r, kb_ = 16 + t0 + r;
            SRu[base + (size_t)ka  * 256] = f2bf(r0[r]);
            SRu[base + (size_t)kb_ * 256] = f2bf(r1[r]);
            SIu[base + (size_t)ka  * 256] = f2bf(i0[r]);
            SIu[base + (size_t)kb_ * 256] = f2bf(i1[r]);
        }
    }
}

// ---------------------------------------------------------------------------
// Kernel C: output (R12 verbatim). grid (128, 4): x = b*64+c, y = d-quarter.
// Exclusive prefix rebuilt inline by walking ALL prior chunk tiles (bf16,
// L2/LLC-resident: 4 MB total).
// ---------------------------------------------------------------------------
__global__ __launch_bounds__(256) void k_attnout(
    const float* __restrict__ KP, const float* __restrict__ QP,
    const bf16* __restrict__ Vb,
    const bf16* __restrict__ SRg, const bf16* __restrict__ SIg,
    float* __restrict__ out)
{
    __shared__ float QPc[32 * 68], KPc[32 * 68], Sl[32 * 36];
    __shared__ float vall[32 * 68], PRl[32 * 68], PIl[32 * 68];
    const int tid = threadIdx.x;
    const int b = blockIdx.x >> 6, c = blockIdx.x & 63;
    const int dh = blockIdx.y;
    const int row0 = b * 2048 + c * 32;

    #pragma unroll
    for (int it = 0; it < 2; ++it) {
        int idx = tid + it * 256, t = idx >> 4, j4 = idx & 15;
        *(v4f*)&QPc[t * 68 + j4 * 4] = *(const v4f*)(QP + (size_t)(row0 + t) * 64 + j4 * 4);
        *(v4f*)&KPc[t * 68 + j4 * 4] = *(const v4f*)(KP + (size_t)(row0 + t) * 64 + j4 * 4);
    }
    {   // V slice bf16 -> fp32 LDS
        int t = tid >> 3, e8 = (tid & 7) * 8;
        s16x8 u = *(const s16x8*)((const unsigned short*)Vb
                                  + (size_t)(row0 + t) * 256 + dh * 64 + e8);
        #pragma unroll
        for (int j = 0; j < 8; ++j) vall[t * 68 + e8 + j] = bf2f((unsigned short)u[j]);
    }
    {   // exclusive-prefix: walk all prior chunk tiles
        int k = tid >> 3, dg = tid & 7;
        float pr[8] = {}, pi[8] = {};
        const unsigned short* SRu = (const unsigned short*)SRg;
        const unsigned short* SIu = (const unsigned short*)SIg;
        size_t sb = ((size_t)(b * 64) * 32 + k) * 256 + dh * 64 + dg * 8;
        #pragma unroll 4
        for (int cp = 0; cp < c; ++cp) {
            s16x8 ur = *(const s16x8*)(SRu + sb + (size_t)cp * 8192);
            s16x8 ui = *(const s16x8*)(SIu + sb + (size_t)cp * 8192);
            #pragma unroll
            for (int j = 0; j < 8; ++j) {
                pr[j] += bf2f((unsigned short)ur[j]);
                pi[j] += bf2f((unsigned short)ui[j]);
            }
        }
        #pragma unroll
        for (int j = 0; j < 8; ++j) {
            PRl[k * 68 + dg * 8 + j] = pr[j];
            PIl[k * 68 + dg * 8 + j] = pi[j];
        }
    }
    __syncthreads();
    {   // S tile (32x32, causal-masked)
        const int sl = tid >> 3, tq = tid & 7;
        float s4[4] = {0.f, 0.f, 0.f, 0.f};
        for (int j4 = 0; j4 < 16; ++j4) {
            v4f q4 = *(const v4f*)&QPc[sl * 68 + j4 * 4];
            #pragma unroll
            for (int i = 0; i < 4; ++i) {
                v4f k4 = *(const v4f*)&KPc[(tq * 4 + i) * 68 + j4 * 4];
                s4[i] += q4[0]*k4[0] + q4[1]*k4[1] + q4[2]*k4[2] + q4[3]*k4[3];
            }
        }
        #pragma unroll
        for (int i = 0; i < 4; ++i) {
            int t = tq * 4 + i;
            Sl[sl * 36 + t] = (t <= sl) ? s4[i] : 0.f;
        }
    }
    __syncthreads();
    const int l = tid & 31, dq = tid >> 5;
    const int d0 = dq * 8;
    float acc[8] = {};
    for (int k = 0; k < 32; ++k) {
        float qc = QPc[l * 68 + k], qs = QPc[l * 68 + 32 + k];
        #pragma unroll
        for (int j4 = 0; j4 < 2; ++j4) {
            v4f pr = *(const v4f*)&PRl[k * 68 + d0 + j4 * 4];
            v4f pi = *(const v4f*)&PIl[k * 68 + d0 + j4 * 4];
            #pragma unroll
            for (int x = 0; x < 4; ++x)
                acc[j4 * 4 + x] += qc * pr[x] + qs * pi[x];
        }
    }
    for (int t = 0; t < 32; ++t) {
        float s = Sl[l * 36 + t];
        #pragma unroll
        for (int j4 = 0; j4 < 2; ++j4) {
            v4f v4_ = *(const v4f*)&vall[t * 68 + d0 + j4 * 4];
            #pragma unroll
            for (int x = 0; x < 4; ++x)
                acc[j4 * 4 + x] = fmaf(s, v4_[x], acc[j4 * 4 + x]);
        }
    }
    const int gl = c * 32 + l;
    const float inv = rsqrtf((float)((gl + 1) * 32));
    const size_t ob = ((size_t)(b * 2048 + gl)) * 256 + dh * 64 + d0;
    #pragma unroll
    for (int j4 = 0; j4 < 2; ++j4) {
        v4f v;
        #pragma unroll
        for (int x = 0; x < 4; ++x) v[x] = acc[j4 * 4 + x] * inv;
        *(v4f*)(out + ob + j4 * 4) = v;
    }
}

// ---------------------------------------------------------------------------
extern "C" void kernel_launch(void* const* d_in, const int* in_sizes, int n_in,
                              void* d_out, int out_size, void* d_ws, size_t ws_size,
                              hipStream_t stream)
{
    const float* x   = (const float*)d_in[0];
    const float* kw1 = (const float*)d_in[1];
    const float* kb1 = (const float*)d_in[2];
    const float* kw2 = (const float*)d_in[3];
    const float* kb2 = (const float*)d_in[4];
    const float* qw1 = (const float*)d_in[5];
    const float* qb1 = (const float*)d_in[6];
    const float* qw2 = (const float*)d_in[7];
    const float* qb2 = (const float*)d_in[8];
    const float* vw  = (const float*)d_in[9];
    const float* vb  = (const float*)d_in[10];
    float* out = (float*)d_out;

    char* ws = (char*)d_ws;
    float* KP  = (float*)ws; ws += (size_t)4096 * 64 * 4;
    float* QP  = (float*)ws; ws += (size_t)4096 * 64 * 4;
    bf16*  Wb  = (bf16*)ws;  ws += (size_t)768 * 256 * 2;
    bf16*  W2b = (bf16*)ws;  ws += (size_t)64 * 256 * 2;
    bf16*  Vb  = (bf16*)ws;  ws += (size_t)4096 * 256 * 2;
    bf16*  SR  = (bf16*)ws;  ws += (size_t)2 * 64 * 32 * 256 * 2;
    bf16*  SI  = (bf16*)ws;  ws += (size_t)2 * 64 * 32 * 256 * 2;

    k_cvtw   <<<104,          256,  0, stream>>>(kw1, qw1, vw, kw2, qw2, Wb, W2b);
    k_fused1 <<<128,          1024, 0, stream>>>(x, Wb, kb1, qb1, vb, W2b, kb2, qb2,
                                                 KP, QP, Vb, SR, SI);
    k_attnout<<<dim3(128, 4), 256,  0, stream>>>(KP, QP, Vb, SR, SI, out);
}

// Round 14
// 52.902 us; speedup vs baseline: 1.9047x; 1.0013x over previous
//
#include <hip/hip_runtime.h>
#include <hip/hip_bf16.h>
#include <math.h>

typedef float v4f   __attribute__((ext_vector_type(4)));
typedef float f32x4 __attribute__((ext_vector_type(4)));
typedef short s16x8 __attribute__((ext_vector_type(8)));
typedef __hip_bfloat16 bf16;

#define PI_F 3.14159265358979323846f

// B=2, L=2048, D=256, K=32. Chunks: 32 rows, 64/batch, 128 total.
// 3 dispatches (priced via R2/R6/R9/R12 cross-round data):
//   cvtw    — pre-convert weights to bf16 ONCE (on-the-fly cvt costs 2x L1
//             bytes + pack VALU in every encode block: R12 regression)
//   fused1  — R6's proven 32-row-chunk encode (bf16 weight loads)
//   attnout — R12's proven full prefix-walk (scanpart dispatch not worth it)

__device__ inline unsigned short f2bf(float f) {
    unsigned int b = __float_as_uint(f);
    unsigned int r = (b + 0x7FFFu + ((b >> 16) & 1u)) >> 16;   // RNE
    return (unsigned short)r;
}
__device__ inline float bf2f(unsigned short u) {
    return __uint_as_float(((unsigned int)u) << 16);
}
__device__ inline void cvt8(const float* __restrict__ src, unsigned short* dst) {
    v4f a = *(const v4f*)src, b = *(const v4f*)(src + 4);
    ushort4 u0, u1;
    u0.x = f2bf(a[0]); u0.y = f2bf(a[1]); u0.z = f2bf(a[2]); u0.w = f2bf(a[3]);
    u1.x = f2bf(b[0]); u1.y = f2bf(b[1]); u1.z = f2bf(b[2]); u1.w = f2bf(b[3]);
    *(ushort4*)dst = u0; *(ushort4*)(dst + 4) = u1;
}

// ---------------------------------------------------------------------------
// Kernel A: one-time weight conversion (R6 verbatim).
// Wb[768][256] = [kw1|qw1|vw] bf16 ; W2b[64][256] = [kw2|qw2] bf16.
// ---------------------------------------------------------------------------
__global__ __launch_bounds__(256) void k_cvtw(
    const float* __restrict__ kw1, const float* __restrict__ qw1,
    const float* __restrict__ vw,  const float* __restrict__ kw2,
    const float* __restrict__ qw2, bf16* __restrict__ Wb, bf16* __restrict__ W2b)
{
    int i8 = blockIdx.x * 256 + threadIdx.x;
    int r = i8 >> 5, c8 = (i8 & 31) * 8;
    const float* src;
    unsigned short* dst;
    if (r < 768) {
        src = (r < 256) ? kw1 + (size_t)r * 256
            : (r < 512) ? qw1 + (size_t)(r - 256) * 256
                        : vw  + (size_t)(r - 512) * 256;
        dst = (unsigned short*)Wb + (size_t)r * 256;
    } else {
        int r2 = r - 768;
        src = (r2 < 32) ? kw2 + (size_t)r2 * 256 : qw2 + (size_t)(r2 - 32) * 256;
        dst = (unsigned short*)W2b + (size_t)r2 * 256;
    }
    cvt8(src + c8, dst + c8);
}

// ---------------------------------------------------------------------------
// Kernel B: fused encode + chunk-state (R6 verbatim). One block per (b,chunk):
// 128 blocks, 1024 threads (16 waves). LDS 58.9 KB (Abf reused as Vt/CK).
// ---------------------------------------------------------------------------
__global__ __launch_bounds__(1024) void k_fused1(
    const float* __restrict__ X,   const bf16* __restrict__ Wbk,
    const float* __restrict__ kb1, const float* __restrict__ qb1,
    const float* __restrict__ vb,  const bf16* __restrict__ W2bk,
    const float* __restrict__ kb2, const float* __restrict__ qb2,
    float* __restrict__ KP, float* __restrict__ QP,
    bf16* __restrict__ Vb, bf16* __restrict__ SRg, bf16* __restrict__ SIg)
{
    __shared__ __align__(16) unsigned char smem[58880];
    unsigned short* Abf = (unsigned short*)smem;            // 32x264 bf16 = 16896 B
    unsigned short* Vt  = (unsigned short*)smem;            // 256x40 = 20480 B (after GEMM1)
    unsigned short* CKc = (unsigned short*)(smem + 20480);  // 32x40 = 2560 B
    unsigned short* CKs = (unsigned short*)(smem + 23040);  // 32x40 = 2560 B
    unsigned short* Hkq = (unsigned short*)(smem + 25600);  // 32x520 = 33280 B

    const int tid  = threadIdx.x;
    const int lane = tid & 63, wid = tid >> 6;          // 16 waves
    const int lrow = lane & 15, lk8 = (lane >> 4) * 8;
    const int t0   = (lane >> 4) * 4;
    const int bb = blockIdx.x >> 6, cc = blockIdx.x & 63;
    const int row0 = bb * 2048 + cc * 32;

    // ---- 1) stage X tile (fp32 -> bf16 LDS) ----
    {
        int r = tid >> 5, c8 = (tid & 31) * 8;
        cvt8(X + (size_t)(row0 + r) * 256 + c8, &Abf[r * 264 + c8]);
    }
    __syncthreads();

    // ---- 2) GEMM1: wave owns cols nb..nb+47 (3 n-frags x 2 m-frags) ----
    const int nb = wid * 48;
    const unsigned short* Wu = (const unsigned short*)Wbk;
    f32x4 acc[2][3] = {};
    for (int k0 = 0; k0 < 256; k0 += 32) {
        s16x8 a[2], b[3];
        #pragma unroll
        for (int mf = 0; mf < 2; ++mf)
            a[mf] = *(const s16x8*)&Abf[(mf * 16 + lrow) * 264 + k0 + lk8];
        #pragma unroll
        for (int nf = 0; nf < 3; ++nf)
            b[nf] = *(const s16x8*)(Wu + (size_t)(nb + nf * 16 + lrow) * 256 + k0 + lk8);
        #pragma unroll
        for (int mf = 0; mf < 2; ++mf)
            #pragma unroll
            for (int nf = 0; nf < 3; ++nf)
                acc[mf][nf] = __builtin_amdgcn_mfma_f32_16x16x32_bf16(
                    a[mf], b[nf], acc[mf][nf], 0, 0, 0);
    }
    __syncthreads();   // all A reads done before Abf region is reused as Vt

    // ---- 3) epilogue -> Hkq / Vt LDS (+ Vb global) ----
    #pragma unroll
    for (int nf = 0; nf < 3; ++nf) {
        int n = nb + nf * 16 + lrow;
        float bias = (n < 256) ? kb1[n] : (n < 512) ? qb1[n - 256] : vb[n - 512];
        #pragma unroll
        for (int mf = 0; mf < 2; ++mf) {
            int tb = mf * 16 + t0;
            if (n < 512) {
                #pragma unroll
                for (int r = 0; r < 4; ++r)
                    Hkq[(tb + r) * 520 + n] = f2bf(tanhf(acc[mf][nf][r] + bias));
            } else {
                int d = n - 512;
                float v0 = acc[mf][nf][0] + bias, v1 = acc[mf][nf][1] + bias;
                float v2 = acc[mf][nf][2] + bias, v3 = acc[mf][nf][3] + bias;
                ushort4 u;
                u.x = f2bf(v0); u.y = f2bf(v1); u.z = f2bf(v2); u.w = f2bf(v3);
                *(ushort4*)&Vt[d * 40 + tb] = u;
                unsigned short* Vg = (unsigned short*)Vb + (size_t)(row0 + tb) * 256 + d;
                Vg[0] = u.x; Vg[256] = u.y; Vg[512] = u.z; Vg[768] = u.w;
            }
        }
    }
    __syncthreads();

    // ---- 4) GEMM2 (waves 0-7): layer-2 + trig ----
    if (wid < 8) {
        const int which = wid >> 2;           // 0=K, 1=Q
        const int q = wid & 3, mf = q >> 1, nf = q & 1;
        const int hoff = which * 256;
        const unsigned short* W2u =
            (const unsigned short*)W2bk + (size_t)(which * 32 + nf * 16 + lrow) * 256;
        f32x4 u = {};
        for (int k0 = 0; k0 < 256; k0 += 32) {
            s16x8 a = *(const s16x8*)&Hkq[(mf * 16 + lrow) * 520 + hoff + k0 + lk8];
            s16x8 b = *(const s16x8*)(W2u + k0 + lk8);
            u = __builtin_amdgcn_mfma_f32_16x16x32_bf16(a, b, u, 0, 0, 0);
        }
        const int outk = nf * 16 + lrow;      // phase index 0..31
        const float bias = (which ? qb2 : kb2)[outk];
        float* dst = which ? QP : KP;
        float cs[4], sn[4];
        #pragma unroll
        for (int r = 0; r < 4; ++r) {
            float ph = tanhf(u[r] + bias) * PI_F;
            float s, c_;
            __sincosf(ph, &s, &c_);
            cs[r] = c_; sn[r] = s;
            int row = mf * 16 + t0 + r;
            dst[(size_t)(row0 + row) * 64 + outk]      = c_;
            dst[(size_t)(row0 + row) * 64 + 32 + outk] = s;
        }
        if (which == 0) {
            ushort4 uc, us;
            uc.x = f2bf(cs[0]); uc.y = f2bf(cs[1]); uc.z = f2bf(cs[2]); uc.w = f2bf(cs[3]);
            us.x = f2bf(sn[0]); us.y = f2bf(sn[1]); us.z = f2bf(sn[2]); us.w = f2bf(sn[3]);
            *(ushort4*)&CKc[outk * 40 + mf * 16 + t0] = uc;
            *(ushort4*)&CKs[outk * 40 + mf * 16 + t0] = us;
        }
    }
    __syncthreads();

    // ---- 5) GEMM3: chunk sums. wave wid owns d-block wid*16..+15 ----
    {
        s16x8 bV = *(const s16x8*)&Vt[(wid * 16 + lrow) * 40 + lk8];
        s16x8 c0 = *(const s16x8*)&CKc[(lrow) * 40 + lk8];
        s16x8 c1 = *(const s16x8*)&CKc[(16 + lrow) * 40 + lk8];
        s16x8 s0 = *(const s16x8*)&CKs[(lrow) * 40 + lk8];
        s16x8 s1 = *(const s16x8*)&CKs[(16 + lrow) * 40 + lk8];
        f32x4 z = {};
        f32x4 r0 = __builtin_amdgcn_mfma_f32_16x16x32_bf16(c0, bV, z, 0, 0, 0);
        f32x4 r1 = __builtin_amdgcn_mfma_f32_16x16x32_bf16(c1, bV, z, 0, 0, 0);
        f32x4 i0 = __builtin_amdgcn_mfma_f32_16x16x32_bf16(s0, bV, z, 0, 0, 0);
        f32x4 i1 = __builtin_amdgcn_mfma_f32_16x16x32_bf16(s1, bV, z, 0, 0, 0);
        const int d = wid * 16 + lrow;
        size_t base = (((size_t)(bb * 64 + cc)) * 32) * 256 + d;
        unsigned short* SRu = (unsigned short*)SRg;
        unsigned short* SIu = (unsigned short*)SIg;
        #pragma unroll
        for (int r = 0; r < 4; ++r) {
            int ka = t0 + r, kb_ = 16 + t0 + r;
            SRu[base + (size_t)ka  * 256] = f2bf(r0[r]);
            SRu[base + (size_t)kb_ * 256] = f2bf(r1[r]);
            SIu[base + (size_t)ka  * 256] = f2bf(i0[r]);
            SIu[base + (size_t)kb_ * 256] = f2bf(i1[r]);
        }
    }
}

// ---------------------------------------------------------------------------
// Kernel C: output (R12 verbatim). grid (128, 4): x = b*64+c, y = d-quarter.
// Exclusive prefix rebuilt inline by walking ALL prior chunk tiles (bf16,
// L2/LLC-resident: 4 MB total).
// ---------------------------------------------------------------------------
__global__ __launch_bounds__(256) void k_attnout(
    const float* __restrict__ KP, const float* __restrict__ QP,
    const bf16* __restrict__ Vb,
    const bf16* __restrict__ SRg, const bf16* __restrict__ SIg,
    float* __restrict__ out)
{
    __shared__ float QPc[32 * 68], KPc[32 * 68], Sl[32 * 36];
    __shared__ float vall[32 * 68], PRl[32 * 68], PIl[32 * 68];
    const int tid = threadIdx.x;
    const int b = blockIdx.x >> 6, c = blockIdx.x & 63;
    const int dh = blockIdx.y;
    const int row0 = b * 2048 + c * 32;

    #pragma unroll
    for (int it = 0; it < 2; ++it) {
        int idx = tid + it * 256, t = idx >> 4, j4 = idx & 15;
        *(v4f*)&QPc[t * 68 + j4 * 4] = *(const v4f*)(QP + (size_t)(row0 + t) * 64 + j4 * 4);
        *(v4f*)&KPc[t * 68 + j4 * 4] = *(const v4f*)(KP + (size_t)(row0 + t) * 64 + j4 * 4);
    }
    {   // V slice bf16 -> fp32 LDS
        int t = tid >> 3, e8 = (tid & 7) * 8;
        s16x8 u = *(const s16x8*)((const unsigned short*)Vb
                                  + (size_t)(row0 + t) * 256 + dh * 64 + e8);
        #pragma unroll
        for (int j = 0; j < 8; ++j) vall[t * 68 + e8 + j] = bf2f((unsigned short)u[j]);
    }
    {   // exclusive-prefix: walk all prior chunk tiles
        int k = tid >> 3, dg = tid & 7;
        float pr[8] = {}, pi[8] = {};
        const unsigned short* SRu = (const unsigned short*)SRg;
        const unsigned short* SIu = (const unsigned short*)SIg;
        size_t sb = ((size_t)(b * 64) * 32 + k) * 256 + dh * 64 + dg * 8;
        #pragma unroll 4
        for (int cp = 0; cp < c; ++cp) {
            s16x8 ur = *(const s16x8*)(SRu + sb + (size_t)cp * 8192);
            s16x8 ui = *(const s16x8*)(SIu + sb + (size_t)cp * 8192);
            #pragma unroll
            for (int j = 0; j < 8; ++j) {
                pr[j] += bf2f((unsigned short)ur[j]);
                pi[j] += bf2f((unsigned short)ui[j]);
            }
        }
        #pragma unroll
        for (int j = 0; j < 8; ++j) {
            PRl[k * 68 + dg * 8 + j] = pr[j];
            PIl[k * 68 + dg * 8 + j] = pi[j];
        }
    }
    __syncthreads();
    {   // S tile (32x32, causal-masked)
        const int sl = tid >> 3, tq = tid & 7;
        float s4[4] = {0.f, 0.f, 0.f, 0.f};
        for (int j4 = 0; j4 < 16; ++j4) {
            v4f q4 = *(const v4f*)&QPc[sl * 68 + j4 * 4];
            #pragma unroll
            for (int i = 0; i < 4; ++i) {
                v4f k4 = *(const v4f*)&KPc[(tq * 4 + i) * 68 + j4 * 4];
                s4[i] += q4[0]*k4[0] + q4[1]*k4[1] + q4[2]*k4[2] + q4[3]*k4[3];
            }
        }
        #pragma unroll
        for (int i = 0; i < 4; ++i) {
            int t = tq * 4 + i;
            Sl[sl * 36 + t] = (t <= sl) ? s4[i] : 0.f;
        }
    }
    __syncthreads();
    const int l = tid & 31, dq = tid >> 5;
    const int d0 = dq * 8;
    float acc[8] = {};
    for (int k = 0; k < 32; ++k) {
        float qc = QPc[l * 68 + k], qs = QPc[l * 68 + 32 + k];
        #pragma unroll
        for (int j4 = 0; j4 < 2; ++j4) {
            v4f pr = *(const v4f*)&PRl[k * 68 + d0 + j4 * 4];
            v4f pi = *(const v4f*)&PIl[k * 68 + d0 + j4 * 4];
            #pragma unroll
            for (int x = 0; x < 4; ++x)
                acc[j4 * 4 + x] += qc * pr[x] + qs * pi[x];
        }
    }
    for (int t = 0; t < 32; ++t) {
        float s = Sl[l * 36 + t];
        #pragma unroll
        for (int j4 = 0; j4 < 2; ++j4) {
            v4f v4_ = *(const v4f*)&vall[t * 68 + d0 + j4 * 4];
            #pragma unroll
            for (int x = 0; x < 4; ++x)
                acc[j4 * 4 + x] = fmaf(s, v4_[x], acc[j4 * 4 + x]);
        }
    }
    const int gl = c * 32 + l;
    const float inv = rsqrtf((float)((gl + 1) * 32));
    const size_t ob = ((size_t)(b * 2048 + gl)) * 256 + dh * 64 + d0;
    #pragma unroll
    for (int j4 = 0; j4 < 2; ++j4) {
        v4f v;
        #pragma unroll
        for (int x = 0; x < 4; ++x) v[x] = acc[j4 * 4 + x] * inv;
        *(v4f*)(out + ob + j4 * 4) = v;
    }
}

// ---------------------------------------------------------------------------
extern "C" void kernel_launch(void* const* d_in, const int* in_sizes, int n_in,
                              void* d_out, int out_size, void* d_ws, size_t ws_size,
                              hipStream_t stream)
{
    const float* x   = (const float*)d_in[0];
    const float* kw1 = (const float*)d_in[1];
    const float* kb1 = (const float*)d_in[2];
    const float* kw2 = (const float*)d_in[3];
    const float* kb2 = (const float*)d_in[4];
    const float* qw1 = (const float*)d_in[5];
    const float* qb1 = (const float*)d_in[6];
    const float* qw2 = (const float*)d_in[7];
    const float* qb2 = (const float*)d_in[8];
    const float* vw  = (const float*)d_in[9];
    const float* vb  = (const float*)d_in[10];
    float* out = (float*)d_out;

    char* ws = (char*)d_ws;
    float* KP  = (float*)ws; ws += (size_t)4096 * 64 * 4;
    float* QP  = (float*)ws; ws += (size_t)4096 * 64 * 4;
    bf16*  Wb  = (bf16*)ws;  ws += (size_t)768 * 256 * 2;
    bf16*  W2b = (bf16*)ws;  ws += (size_t)64 * 256 * 2;
    bf16*  Vb  = (bf16*)ws;  ws += (size_t)4096 * 256 * 2;
    bf16*  SR  = (bf16*)ws;  ws += (size_t)2 * 64 * 32 * 256 * 2;
    bf16*  SI  = (bf16*)ws;  ws += (size_t)2 * 64 * 32 * 256 * 2;

    k_cvtw   <<<104,          256,  0, stream>>>(kw1, qw1, vw, kw2, qw2, Wb, W2b);
    k_fused1 <<<128,          1024, 0, stream>>>(x, Wb, kb1, qb1, vb, W2b, kb2, qb2,
                                                 KP, QP, Vb, SR, SI);
    k_attnout<<<dim3(128, 4), 256,  0, stream>>>(KP, QP, Vb, SR, SI, out);
}